// Round 7
// baseline (209.024 us; speedup 1.0000x reference)
//
#include <hip/hip_runtime.h>
#include <math.h>

// Side-window filter, 3 iterations fused, FP32, bit-exact vs the np reference
// (verified absmax==0.0 since round 4): each directional conv is a sequential
// fp32 FMA chain over taps in row-major (ky,kx) order, acc starting at 0,
// weights fp32(1/15), fp32(1/9), fp32(fp32(1/9)/9). Zero-padded taps are exact
// no-ops. Intermediates fp32; out-of-image intermediate pixels zeroed (next
// iteration zero-pads at the image boundary).
//
// Round 7: 48x64 tile (LDS 34.4 KB -> 4 blocks/CU, occupancy 37.5%->50%) at
// +2% halo work; 8-px segments for the W2%8==0 steps (fewer loop trips, LDS
// reads 20->15 b128 per 8px, shift instead of magic-div for SC=8).
//
// Direction supports (with the reference's normalization bug):
//   d0 L  = rows[-2..2] x cols[-2..0] * (1/15)
//   d1 R  = rows[-2..2] x cols[0..2]  * (1/15)
//   d2 U  = rows[-2..0] x cols[-2..2] * (1/15)
//   d3 D  = rows[0..2]  x cols[-2..2] * (1/15)
//   d4 NW = rows[-2..0] x cols[-2..0] * (1/9)
//   d5 NE = NW support * (1/81)   (bug: NE = new NW / 9)
//   d6 SW = rows[0..2]  x cols[-2..0] * (1/9)
//   d7 SE = SW support * (1/81)   (bug: SE = new SW / 9)

typedef float f4v __attribute__((ext_vector_type(4)));
typedef float f2v __attribute__((ext_vector_type(2), aligned(8)));

#define TW 64
#define TH 48

// One SWF iteration. X: (H2+4) x (W2+4) fp32 LDS tile (pitch W2+4), zero-pad.
// Y: H2 x W2 (pitch W2), zeroed outside the 768x768 image (gy0,gx0 = global
// coords of Y[0][0]); if LAST, write fp32 to outp (pitch 768).
// PXW = pixels per segment (4 or 8); requires W2 % PXW == 0.
template<int H2, int W2, int PXW, bool LAST>
__device__ __forceinline__ void step(const float* __restrict__ X,
                                     float* __restrict__ Y,
                                     float* __restrict__ outp,
                                     int gy0, int gx0, int tid) {
    constexpr int PW = W2 + 4;
    constexpr int SC = W2 / PXW;
    constexpr int NSEG = H2 * SC;
    constexpr int WF = PXW + 4;          // window floats per row
    const float w15 = 1.0f / 15.0f;
    const float w9  = 1.0f / 9.0f;
    const float w81 = (1.0f / 9.0f) / 9.0f;

    // block-uniform: every output pixel of this step inside the image?
    const bool interior = (gy0 >= 0) && (gx0 >= 0) &&
                          (gy0 + H2 <= 768) && (gx0 + W2 <= 768);

    for (int s = tid; s < NSEG; s += 256) {
        const int y  = s / SC;
        const int xs = (s - y * SC) * PXW;
        const float* rp = X + y * PW + xs;   // 16B-aligned (pitches mult of 4)

        // acc[dir][px]; per-accumulator op order = rows ascending (r loop),
        // cols ascending within row — the verified bit-exact chain.
        float acc[8][PXW];
        #pragma unroll
        for (int d = 0; d < 8; d++)
            #pragma unroll
            for (int j = 0; j < PXW; j++) acc[d][j] = 0.0f;
        float ctr[PXW];

        #pragma unroll
        for (int r = 0; r < 5; r++) {
            const float* p = rp + r * PW;
            float w[WF];
            #pragma unroll
            for (int q = 0; q < WF / 4; q++)
                *(f4v*)&w[4 * q] = *(const f4v*)(p + 4 * q);

            #pragma unroll
            for (int j = 0; j < PXW; j++) {
                // full-height: L (cols j..j+2), R (cols j+2..j+4)
                acc[0][j] = fmaf(w15, w[j + 0], acc[0][j]);
                acc[0][j] = fmaf(w15, w[j + 1], acc[0][j]);
                acc[0][j] = fmaf(w15, w[j + 2], acc[0][j]);
                acc[1][j] = fmaf(w15, w[j + 2], acc[1][j]);
                acc[1][j] = fmaf(w15, w[j + 3], acc[1][j]);
                acc[1][j] = fmaf(w15, w[j + 4], acc[1][j]);
                if (r < 3) {  // U, NW, NE
                    acc[2][j] = fmaf(w15, w[j + 0], acc[2][j]);
                    acc[2][j] = fmaf(w15, w[j + 1], acc[2][j]);
                    acc[2][j] = fmaf(w15, w[j + 2], acc[2][j]);
                    acc[2][j] = fmaf(w15, w[j + 3], acc[2][j]);
                    acc[2][j] = fmaf(w15, w[j + 4], acc[2][j]);
                    acc[4][j] = fmaf(w9,  w[j + 0], acc[4][j]);
                    acc[4][j] = fmaf(w9,  w[j + 1], acc[4][j]);
                    acc[4][j] = fmaf(w9,  w[j + 2], acc[4][j]);
                    acc[5][j] = fmaf(w81, w[j + 0], acc[5][j]);
                    acc[5][j] = fmaf(w81, w[j + 1], acc[5][j]);
                    acc[5][j] = fmaf(w81, w[j + 2], acc[5][j]);
                }
                if (r >= 2) {  // D, SW, SE
                    acc[3][j] = fmaf(w15, w[j + 0], acc[3][j]);
                    acc[3][j] = fmaf(w15, w[j + 1], acc[3][j]);
                    acc[3][j] = fmaf(w15, w[j + 2], acc[3][j]);
                    acc[3][j] = fmaf(w15, w[j + 3], acc[3][j]);
                    acc[3][j] = fmaf(w15, w[j + 4], acc[3][j]);
                    acc[6][j] = fmaf(w9,  w[j + 0], acc[6][j]);
                    acc[6][j] = fmaf(w9,  w[j + 1], acc[6][j]);
                    acc[6][j] = fmaf(w9,  w[j + 2], acc[6][j]);
                    acc[7][j] = fmaf(w81, w[j + 0], acc[7][j]);
                    acc[7][j] = fmaf(w81, w[j + 1], acc[7][j]);
                    acc[7][j] = fmaf(w81, w[j + 2], acc[7][j]);
                }
                if (r == 2) ctr[j] = w[j + 2];
            }
        }

        float res[PXW];
        #pragma unroll
        for (int j = 0; j < PXW; j++) {
            const float c = ctr[j];
            const float e0 = acc[0][j] - c, e1 = acc[1][j] - c;
            const float e2 = acc[2][j] - c, e3 = acc[3][j] - c;
            const float e4 = acc[4][j] - c, e5 = acc[5][j] - c;
            const float e6 = acc[6][j] - c, e7 = acc[7][j] - c;
            // tournament argmin on |d|; strict < keeps lowest index on ties
            // (matches jnp.argmin); |x| folds into VOP3 abs modifiers
            float m01 = (fabsf(e1) < fabsf(e0)) ? e1 : e0;
            float m23 = (fabsf(e3) < fabsf(e2)) ? e3 : e2;
            float m45 = (fabsf(e5) < fabsf(e4)) ? e5 : e4;
            float m67 = (fabsf(e7) < fabsf(e6)) ? e7 : e6;
            float mA  = (fabsf(m23) < fabsf(m01)) ? m23 : m01;
            float mB  = (fabsf(m67) < fabsf(m45)) ? m67 : m45;
            float bd  = (fabsf(mB)  < fabsf(mA))  ? mB  : mA;
            res[j] = c + bd;
        }

        if (LAST) {
            #pragma unroll
            for (int q = 0; q < PXW / 4; q++)
                *(f4v*)(outp + y * 768 + xs + 4 * q) = *(const f4v*)&res[4 * q];
        } else {
            if (!interior) {
                // zero outside the image: next iter zero-pads at the boundary
                const bool rowin = ((unsigned)(gy0 + y) < 768u);
                #pragma unroll
                for (int j = 0; j < PXW; j++)
                    res[j] = (rowin && (unsigned)(gx0 + xs + j) < 768u)
                                 ? res[j] : 0.0f;
            }
            #pragma unroll
            for (int q = 0; q < PXW / 4; q++)
                *(f4v*)(Y + y * W2 + xs + 4 * q) = *(const f4v*)&res[4 * q];
        }
    }
    __syncthreads();
}

// LDS: A = 60x76 fp32 (iter1 input; reused as iter2 output 52x68) = 18240 B,
//      B = 56x72 fp32 (iter1 output = iter2 input) = 16128 B. Total 34368 B
//      -> 4 blocks/CU (16 waves/CU, 50% occupancy).
__global__ __launch_bounds__(256) void swf_fused(const float* __restrict__ in,
                                                 float* __restrict__ out) {
    __shared__ __align__(16) float A[60 * 76];
    __shared__ __align__(16) float B[56 * 72];

    const int tid = threadIdx.x;
    const int tx0 = blockIdx.x * TW;
    const int ty0 = blockIdx.y * TH;
    const long long base = (long long)blockIdx.z * (768 * 768);
    const float* inp = in + base;

    // load tile rows ty0-6..ty0+53, cols tx0-6..tx0+69, zero-padded.
    // float2 granularity: global col tx0-6 is even -> 8B aligned.
    for (int i = tid; i < 60 * 38; i += 256) {
        const int ly  = i / 38;
        const int lx2 = i - ly * 38;
        const int gy  = ty0 + ly - 6;
        const int gx  = tx0 + lx2 * 2 - 6;
        f2v v = {0.0f, 0.0f};
        if ((unsigned)gy < 768u) {
            const float* g = inp + gy * 768 + gx;
            if ((unsigned)gx < 767u) {            // both lanes inside
                v = *(const f2v*)g;
            } else {                               // x-edge: per-lane
                if ((unsigned)gx < 768u)       v.x = g[0];
                if ((unsigned)(gx + 1) < 768u) v.y = g[1];
            }
        }
        *(f2v*)(A + ly * 76 + lx2 * 2) = v;
    }
    __syncthreads();

    step<56, 72, 8, false>(A, B, nullptr, ty0 - 4, tx0 - 4, tid);  // iter1 A->B
    step<52, 68, 4, false>(B, A, nullptr, ty0 - 2, tx0 - 2, tid);  // iter2 B->A
    step<48, 64, 8, true >(A, nullptr,                             // iter3 A->out
                           out + base + (long long)ty0 * 768 + tx0,
                           ty0, tx0, tid);
}

extern "C" void kernel_launch(void* const* d_in, const int* in_sizes, int n_in,
                              void* d_out, int out_size, void* d_ws, size_t ws_size,
                              hipStream_t stream) {
    const float* x = (const float*)d_in[0];
    float* out = (float*)d_out;

    dim3 grid(768 / TW, 768 / TH, 24);   // 12 x 16 x 24 = 4608 blocks
    dim3 block(256);
    swf_fused<<<grid, block, 0, stream>>>(x, out);
}